// Round 5
// baseline (1782.623 us; speedup 1.0000x reference)
//
#include <hip/hip_runtime.h>
#include <math.h>

#define EMBED 768
#define HEADS 12
#define DH 64
#define DEPTH 6
#define MLP_DIM 3072
#define N_REAL 2049
#define SP 2112            // fp32 buffer row padding
#define SPAD 2176          // bf16 activation row padding (17 tiles * 128)
#define NEGV (-1e9f)

typedef __attribute__((ext_vector_type(8))) short short8;
typedef __attribute__((ext_vector_type(4))) float f32x4;

__device__ __forceinline__ unsigned short f2bf(float f) {
    union { float f; unsigned u; } x; x.f = f;
    unsigned r = x.u + 0x7FFF + ((x.u >> 16) & 1);
    return (unsigned short)(r >> 16);
}
__device__ __forceinline__ float bf2f(unsigned short s) {
    union { unsigned u; float f; } x; x.u = (unsigned)s << 16;
    return x.f;
}

// async global->LDS, 16B per lane; LDS dest = wave-uniform base + lane*16
__device__ __forceinline__ void gload16(const unsigned short* g, unsigned short* l) {
    __builtin_amdgcn_global_load_lds(
        (const __attribute__((address_space(1))) void*)g,
        (__attribute__((address_space(3))) void*)l, 16, 0, 0);
}

// ---------------- im2col: x -> patches bf16 [2048][1024] ----------------
__global__ void im2col_kernel(const float* __restrict__ x, unsigned short* __restrict__ p) {
    const int pi = blockIdx.x;            // 0..2047
    const int d = pi >> 8, rr = (pi >> 4) & 15, cc = pi & 15;
    const int t = threadIdx.x;            // 256
    #pragma unroll
    for (int u = 0; u < 4; ++u) {
        int i = u * 256 + t;              // 0..1023
        int kd = i >> 8, kr = (i >> 4) & 15, kc = i & 15;
        float v = x[(size_t)(d * 4 + kd) * 65536 + (rr * 16 + kr) * 256 + (cc * 16 + kc)];
        p[(size_t)pi * 1024 + i] = f2bf(v);
    }
}

// ---------------- weight pack: fp32 -> staging-order bf16 blobs ----------------
// Blob entry (g*512 + l*8 + e) holds element (row = g*16 + (l>>2),
// k = ((l&3)^((l>>3)&3))*8 + e) of the 128(row=N-dim) x 32(K) tile --
// identical to the GEMM's gload/ds_read mapping (swizzle baked in).
// pack_KN: src is [K][N] row-major (wq/wk/wv/wo/w1/w2 layouts).
__global__ void pack_KN_kernel(const float* __restrict__ src, unsigned short* __restrict__ dst,
                               int N, int K) {
    __shared__ float lf[32][128];
    const int bn = blockIdx.x, bk = blockIdx.y;
    const int t = threadIdx.x;
    {
        const int kk = t >> 3, ch = t & 7;
        const float4* s = (const float4*)(src + (size_t)(bk * 32 + kk) * N + bn * 128 + ch * 16);
        float4 v0 = s[0], v1 = s[1], v2 = s[2], v3 = s[3];
        float* d = &lf[kk][ch * 16];
        ((float4*)d)[0] = v0; ((float4*)d)[1] = v1; ((float4*)d)[2] = v2; ((float4*)d)[3] = v3;
    }
    __syncthreads();
    unsigned short ov[16];
    const int base = t * 16;
    #pragma unroll
    for (int e2 = 0; e2 < 16; ++e2) {
        const int idx = base + e2;
        const int g = idx >> 9, l = (idx >> 3) & 63, e = idx & 7;
        const int row = g * 16 + (l >> 2);
        const int kloc = (((l & 3) ^ ((l >> 3) & 3)) << 3) + e;
        ov[e2] = f2bf(lf[kloc][row]);
    }
    unsigned short* o = dst + ((size_t)bn * gridDim.y + bk) * 4096 + base;
    ((short8*)o)[0] = *(short8*)&ov[0];
    ((short8*)o)[1] = *(short8*)&ov[8];
}

// pack_NK: src is [N][K] row-major (conv_w layout: [768][1024]).
__global__ void pack_NK_kernel(const float* __restrict__ src, unsigned short* __restrict__ dst,
                               int N, int K) {
    __shared__ float lf[32][128];
    const int bn = blockIdx.x, bk = blockIdx.y;
    const int t = threadIdx.x;
    {
        const int row = t >> 1, h = t & 1;
        const float4* s = (const float4*)(src + (size_t)(bn * 128 + row) * K + bk * 32 + h * 16);
        float4 v0 = s[0], v1 = s[1], v2 = s[2], v3 = s[3];
        float tmp[16];
        ((float4*)tmp)[0] = v0; ((float4*)tmp)[1] = v1; ((float4*)tmp)[2] = v2; ((float4*)tmp)[3] = v3;
        #pragma unroll
        for (int u = 0; u < 16; ++u) lf[h * 16 + u][row] = tmp[u];
    }
    __syncthreads();
    unsigned short ov[16];
    const int base = t * 16;
    #pragma unroll
    for (int e2 = 0; e2 < 16; ++e2) {
        const int idx = base + e2;
        const int g = idx >> 9, l = (idx >> 3) & 63, e = idx & 7;
        const int row = g * 16 + (l >> 2);
        const int kloc = (((l & 3) ^ ((l >> 3) & 3)) << 3) + e;
        ov[e2] = f2bf(lf[kloc][row]);
    }
    unsigned short* o = dst + ((size_t)bn * gridDim.y + bk) * 4096 + base;
    ((short8*)o)[0] = *(short8*)&ov[0];
    ((short8*)o)[1] = *(short8*)&ov[8];
}

// ---------------- qkv bias concat (all layers) ----------------
__global__ void concat_bias_kernel(const float* __restrict__ bq, const float* __restrict__ bk,
                                   const float* __restrict__ bv, float* __restrict__ bqkv) {
    int i = blockIdx.x * 256 + threadIdx.x;
    if (i >= DEPTH * 2304) return;
    int L = i / 2304, j = i - L * 2304;
    float v = (j < 768) ? bq[L * 768 + j] : (j < 1536) ? bk[L * 768 + j - 768] : bv[L * 768 + j - 1536];
    bqkv[i] = v;
}

__global__ void cls_init_kernel(const float* __restrict__ cls,
                                const float* __restrict__ pos,
                                float* __restrict__ h) {
    int e = blockIdx.x * 256 + threadIdx.x;
    if (e < EMBED) h[e] = cls[e] + pos[e];
}

// ---------------- layernorm: one block per row, optional bf16 output ----------------
template<bool BF>
__global__ void ln_kernel(const float* __restrict__ in, void* __restrict__ outv,
                          const float* __restrict__ w, const float* __restrict__ b,
                          int M) {
    int row = blockIdx.x;
    if (row >= M) return;
    const float* xr = in + (size_t)row * EMBED;
    int tid = threadIdx.x;
    float v0 = xr[tid], v1 = xr[tid + 256], v2 = xr[tid + 512];
    __shared__ float red[4];
    float s = v0 + v1 + v2;
    #pragma unroll
    for (int o = 32; o > 0; o >>= 1) s += __shfl_down(s, o);
    if ((tid & 63) == 0) red[tid >> 6] = s;
    __syncthreads();
    float mean = (red[0] + red[1] + red[2] + red[3]) * (1.0f / 768.0f);
    __syncthreads();
    float d0 = v0 - mean, d1 = v1 - mean, d2 = v2 - mean;
    float q2 = d0 * d0 + d1 * d1 + d2 * d2;
    #pragma unroll
    for (int o = 32; o > 0; o >>= 1) q2 += __shfl_down(q2, o);
    if ((tid & 63) == 0) red[tid >> 6] = q2;
    __syncthreads();
    float var = (red[0] + red[1] + red[2] + red[3]) * (1.0f / 768.0f);
    float rstd = 1.0f / sqrtf(var + 1e-5f);
    float o0 = d0 * rstd * w[tid]       + b[tid];
    float o1 = d1 * rstd * w[tid + 256] + b[tid + 256];
    float o2 = d2 * rstd * w[tid + 512] + b[tid + 512];
    if (BF) {
        unsigned short* orow = (unsigned short*)outv + (size_t)row * EMBED;
        orow[tid] = f2bf(o0); orow[tid + 256] = f2bf(o1); orow[tid + 512] = f2bf(o2);
    } else {
        float* orow = (float*)outv + (size_t)row * EMBED;
        orow[tid] = o0; orow[tid + 256] = o1; orow[tid + 512] = o2;
    }
}

// ---------------- bf16 MFMA GEMM: packed-B streaming + 3-deep pipeline ----------------
// A: bf16 [M][K] row-major (rows padded). Bp: packed blobs [N/128][K/32][4096].
// C = [C +] act(A@B + bias).  MODE: 0 store f32, 1 accum f32, 2 store bf16. ACT: 0/1 gelu.
// 128x128 tile, BK=32, 256 threads = 4 waves, each wave a 64x64 sub-tile.
template<int ACT, int MODE>
__global__ __launch_bounds__(256)
void gemm_bf16(const unsigned short* __restrict__ A, const unsigned short* __restrict__ Bp,
               const float* __restrict__ bias, void* __restrict__ Cv,
               int M, int N, int K) {
    __shared__ unsigned short Al[3 * 4096];
    __shared__ unsigned short Bl[3 * 4096];
    const int tid = threadIdx.x;
    const int lane = tid & 63;
    const int w4 = tid >> 6;                  // wave id 0..3
    const int wm = w4 >> 1, wn = w4 & 1;
    const int row0 = blockIdx.y * 128, col0 = blockIdx.x * 128;
    const int nkt = K >> 5;

    f32x4 acc[4][4];
    #pragma unroll
    for (int mi = 0; mi < 4; ++mi)
        #pragma unroll
        for (int ni = 0; ni < 4; ++ni)
            #pragma unroll
            for (int j = 0; j < 4; ++j) acc[mi][ni][j] = 0.0f;

    const int ksrc = (lane & 3) ^ ((lane >> 3) & 3);          // pre-swizzled A source k-octet
    const int lrow_l = lane >> 2;                             // row within 16-row group
    const int ln15 = lane & 15;
    const int kq = lane >> 4;
    const int kswz = (kq ^ ((ln15 >> 1) & 3)) * 8;
    const int arow_base = (wm * 64 + ln15) * 32 + kswz;
    const int brow_base = (wn * 64 + ln15) * 32 + kswz;

    const unsigned short* Abase = A + (size_t)row0 * K + ksrc * 8;
    const unsigned short* Bbase = Bp + (size_t)blockIdx.x * nkt * 4096 + lane * 8;

    auto STAGE = [&](int t, int b) {
        const int kt = t * 32;
        const unsigned short* Bblob = Bbase + (size_t)t * 4096;
        #pragma unroll
        for (int j = 0; j < 2; ++j) {
            const int g = w4 + j * 4;                         // 16-row group 0..7
            gload16(Abase + (size_t)(g * 16 + lrow_l) * K + kt, &Al[b * 4096 + g * 512]);
            gload16(Bblob + g * 512, &Bl[b * 4096 + g * 512]);
        }
    };

    const int nt = nkt;
    STAGE(0, 0);
    STAGE(1, 1);
    asm volatile("s_waitcnt vmcnt(4)" ::: "memory");   // tile 0 landed, tile 1 in flight
    __builtin_amdgcn_s_barrier();
    __builtin_amdgcn_sched_barrier(0);

    int cur = 0;
    for (int t = 0; t < nt; ++t) {
        if (t + 2 < nt) STAGE(t + 2, (cur + 2) % 3);
        short8 af[4], bfr[4];
        const int abase = cur * 4096 + arow_base;
        const int bbase = cur * 4096 + brow_base;
        #pragma unroll
        for (int mi = 0; mi < 4; ++mi)
            af[mi] = *(const short8*)&Al[abase + mi * 512];
        #pragma unroll
        for (int ni = 0; ni < 4; ++ni)
            bfr[ni] = *(const short8*)&Bl[bbase + ni * 512];
        __builtin_amdgcn_s_setprio(1);
        #pragma unroll
        for (int mi = 0; mi < 4; ++mi)
            #pragma unroll
            for (int ni = 0; ni < 4; ++ni)
                acc[mi][ni] = __builtin_amdgcn_mfma_f32_16x16x32_bf16(af[mi], bfr[ni], acc[mi][ni], 0, 0, 0);
        __builtin_amdgcn_s_setprio(0);
        if (t + 2 < nt) {
            asm volatile("s_waitcnt vmcnt(4)" ::: "memory");
        } else if (t + 1 < nt) {
            asm volatile("s_waitcnt vmcnt(0)" ::: "memory");
        }
        if (t + 1 < nt) {
            __builtin_amdgcn_s_barrier();
            __builtin_amdgcn_sched_barrier(0);
        }
        cur = (cur == 2) ? 0 : cur + 1;
    }

    float* Cf = (float*)Cv;
    unsigned short* Cb = (unsigned short*)Cv;
    #pragma unroll
    for (int mi = 0; mi < 4; ++mi) {
        #pragma unroll
        for (int ni = 0; ni < 4; ++ni) {
            const int col = col0 + wn * 64 + ni * 16 + ln15;
            const float bb = bias[col];
            #pragma unroll
            for (int j = 0; j < 4; ++j) {
                const int row = row0 + wm * 64 + mi * 16 + kq * 4 + j;
                if (row < M) {
                    float v = acc[mi][ni][j] + bb;
                    if (ACT == 1) v = 0.5f * v * (1.0f + erff(v * 0.70710678118654752f));
                    if (MODE == 0)      Cf[(size_t)row * N + col] = v;
                    else if (MODE == 1) Cf[(size_t)row * N + col] += v;
                    else                Cb[(size_t)row * N + col] = f2bf(v);
                }
            }
        }
    }
}

// ---------------- dilated attention (bf16 qkv in, bf16 Obr out) ----------------
__global__ __launch_bounds__(256, 1)
void attn_kernel(const unsigned short* __restrict__ qkv,
                 unsigned short* __restrict__ Obr, float* __restrict__ Lbr) {
    const int bx = blockIdx.x, hh = blockIdx.y;
    int b, n;
    if      (bx < 17) { b = 0; n = bx; }
    else if (bx < 26) { b = 1; n = bx - 17; }
    else if (bx < 31) { b = 2; n = bx - 26; }
    else if (bx < 34) { b = 3; n = bx - 31; }
    else              { b = 4; n = bx - 34; }
    const int r = 1 << b;
    const int w = 128 << b;
    const int hb = hh & (r - 1);
    const int base = n * w + hb;

    __shared__ float ks[128][64];
    __shared__ float vs[128][64];
    const int tid = threadIdx.x;
    {
        int j = tid >> 1, hf = tid & 1;
        int pos = base + r * j;
        float* kd = &ks[j][hf * 32];
        float* vd = &vs[j][hf * 32];
        if (pos < N_REAL) {
            const short8* kp = (const short8*)(qkv + (size_t)pos * 2304 + 768  + hh * 64 + hf * 32);
            const short8* vp = (const short8*)(qkv + (size_t)pos * 2304 + 1536 + hh * 64 + hf * 32);
            #pragma unroll
            for (int u = 0; u < 4; ++u) {
                short8 kv = kp[u], vv = vp[u];
                #pragma unroll
                for (int e = 0; e < 8; ++e) {
                    kd[u * 8 + e] = bf2f((unsigned short)kv[e]);
                    vd[u * 8 + e] = bf2f((unsigned short)vv[e]);
                }
            }
        } else {
            #pragma unroll
            for (int u = 0; u < 32; ++u) { kd[u] = 0.f; vd[u] = 0.f; }
        }
    }
    __syncthreads();

    const int qi = tid >> 1, hf = tid & 1;
    const int qpos = base + r * qi;

    float qr[64];
    if (qpos < N_REAL) {
        const short8* qs = (const short8*)(qkv + (size_t)qpos * 2304 + hh * 64);
        #pragma unroll
        for (int u = 0; u < 8; ++u) {
            short8 qv = qs[u];
            #pragma unroll
            for (int e = 0; e < 8; ++e) qr[u * 8 + e] = bf2f((unsigned short)qv[e]);
        }
    } else {
        #pragma unroll
        for (int u = 0; u < 64; ++u) qr[u] = 0.f;
    }

    float s[64];
    const float scale = 0.125f;
    #pragma unroll
    for (int jj = 0; jj < 64; ++jj) {
        const int key = hf * 64 + jj;
        const int kpos = base + r * key;
        float acc = 0.f;
        const float4* kr4 = (const float4*)&ks[key][0];
        #pragma unroll
        for (int u = 0; u < 16; ++u) {
            float4 t = kr4[u];
            acc += qr[4*u] * t.x + qr[4*u+1] * t.y + qr[4*u+2] * t.z + qr[4*u+3] * t.w;
        }
        s[jj] = (kpos < N_REAL) ? acc * scale : NEGV;
    }
    float m = NEGV;
    #pragma unroll
    for (int jj = 0; jj < 64; ++jj) m = fmaxf(m, s[jj]);
    m = fmaxf(m, __shfl_xor(m, 1));
    float sum = 0.f;
    #pragma unroll
    for (int jj = 0; jj < 64; ++jj) { s[jj] = expf(s[jj] - m); sum += s[jj]; }
    sum += __shfl_xor(sum, 1);
    float o[64];
    #pragma unroll
    for (int u = 0; u < 64; ++u) o[u] = 0.f;
    #pragma unroll
    for (int jj = 0; jj < 64; ++jj) {
        const int key = hf * 64 + jj;
        const float p = s[jj];
        const float4* vr4 = (const float4*)&vs[key][0];
        #pragma unroll
        for (int u = 0; u < 16; ++u) {
            float4 t = vr4[u];
            o[4*u]   += p * t.x;
            o[4*u+1] += p * t.y;
            o[4*u+2] += p * t.z;
            o[4*u+3] += p * t.w;
        }
    }
    #pragma unroll
    for (int u = 0; u < 64; ++u) o[u] += __shfl_xor(o[u], 1);

    if (hf == 0 && qpos < N_REAL) {
        float inv = 1.0f / sum;
        unsigned short* od = Obr + ((size_t)b * N_REAL + qpos) * EMBED + hh * 64;
        #pragma unroll
        for (int u = 0; u < 64; ++u) od[u] = f2bf(o[u] * inv);
        Lbr[((size_t)b * SP + qpos) * HEADS + hh] = m + logf(sum);
    }
}

// ---------------- branch combine -> bf16 (validity derived) ----------------
__global__ void combine_kernel(const unsigned short* __restrict__ Obr, const float* __restrict__ Lbr,
                               unsigned short* __restrict__ out) {
    int gid = blockIdx.x * 256 + threadIdx.x;
    if (gid >= N_REAL * EMBED) return;
    int p = gid / EMBED, e = gid - p * EMBED;
    int h = e >> 6;
    float l[5];
    float mx = NEGV;
    #pragma unroll
    for (int b = 0; b < 5; ++b) {
        const int rm = (1 << b) - 1;
        l[b] = ((p & rm) == (h & rm)) ? Lbr[((size_t)b * SP + p) * HEADS + h] : NEGV;
        mx = fmaxf(mx, l[b]);
    }
    float wsum = 0.f, acc = 0.f;
    #pragma unroll
    for (int b = 0; b < 5; ++b) {
        if (l[b] > NEGV * 0.5f) {
            float wt = expf(l[b] - mx);
            wsum += wt;
            acc += wt * bf2f(Obr[((size_t)b * N_REAL + p) * EMBED + e]);
        }
    }
    out[(size_t)p * EMBED + e] = f2bf(acc / wsum);
}

// ---------------- host orchestration ----------------
extern "C" void kernel_launch(void* const* d_in, const int* in_sizes, int n_in,
                              void* d_out, int out_size, void* d_ws, size_t ws_size,
                              hipStream_t stream) {
    const float* x      = (const float*)d_in[0];
    const float* conv_w = (const float*)d_in[1];
    const float* conv_b = (const float*)d_in[2];
    const float* cls    = (const float*)d_in[3];
    const float* pos    = (const float*)d_in[4];
    const float* ln1w   = (const float*)d_in[5];
    const float* ln1b   = (const float*)d_in[6];
    const float* wq     = (const float*)d_in[7];
    const float* bq     = (const float*)d_in[8];
    const float* wk     = (const float*)d_in[9];
    const float* bk     = (const float*)d_in[10];
    const float* wv     = (const float*)d_in[11];
    const float* bv     = (const float*)d_in[12];
    const float* wo     = (const float*)d_in[13];
    const float* bo     = (const float*)d_in[14];
    const float* ln2w   = (const float*)d_in[15];
    const float* ln2b   = (const float*)d_in[16];
    const float* w1     = (const float*)d_in[17];
    const float* b1     = (const float*)d_in[18];
    const float* w2     = (const float*)d_in[19];
    const float* b2     = (const float*)d_in[20];
    const float* lnfw   = (const float*)d_in[21];
    const float* lnfb   = (const float*)d_in[22];

    float* ws = (float*)d_ws;
    // fp32 buffers
    float* h     = ws;  ws += (size_t)SP * EMBED;            // residual stream
    float* Lbr   = ws;  ws += (size_t)5 * SP * HEADS;
    float* bqkv  = ws;  ws += (size_t)DEPTH * 2304;
    // bf16 buffers (ushort); all blob pools are 16B-aligned (ws starts aligned)
    unsigned short* qkv_bf   = (unsigned short*)ws;  ws += (size_t)SPAD * 2304 / 2;
    unsigned short* xln_bf   = (unsigned short*)ws;  ws += (size_t)SPAD * EMBED / 2;
    unsigned short* attn_bf  = (unsigned short*)ws;  ws += (size_t)SPAD * EMBED / 2;
    unsigned short* mid_bf   = (unsigned short*)ws;  ws += (size_t)SPAD * MLP_DIM / 2;
    unsigned short* patch_bf = (unsigned short*)ws;  ws += (size_t)2048 * 1024 / 2;
    unsigned short* convw_pk = (unsigned short*)ws;  ws += (size_t)EMBED * 1024 / 2;
    unsigned short* Obr      = (unsigned short*)ws;  ws += (size_t)5 * N_REAL * EMBED / 2 + 64;
    unsigned short* wqkv_pk  = (unsigned short*)ws;  ws += (size_t)2304 * EMBED / 2;   // [18][24][4096]
    unsigned short* wo_pk    = (unsigned short*)ws;  ws += (size_t)EMBED * EMBED / 2;  // [6][24][4096]
    unsigned short* w1_pk    = (unsigned short*)ws;  ws += (size_t)MLP_DIM * EMBED / 2;// [24][24][4096]
    unsigned short* w2_pk    = (unsigned short*)ws;  ws += (size_t)EMBED * MLP_DIM / 2;// [6][96][4096]

    // ---- embed ----
    im2col_kernel<<<2048, 256, 0, stream>>>(x, patch_bf);
    pack_NK_kernel<<<dim3(6, 32), 256, 0, stream>>>(conv_w, convw_pk, EMBED, 1024);
    concat_bias_kernel<<<(DEPTH * 2304 + 255) / 256, 256, 0, stream>>>(bq, bk, bv, bqkv);
    cls_init_kernel<<<3, 256, 0, stream>>>(cls, pos, h);
    hipMemcpyAsync(h + EMBED, pos + EMBED, (size_t)2048 * EMBED * sizeof(float),
                   hipMemcpyDeviceToDevice, stream);
    // patch GEMM: h(rows 1..2048) += patches @ conv_w^T + conv_b
    gemm_bf16<0, 1><<<dim3(6, 16), 256, 0, stream>>>(patch_bf, convw_pk, conv_b,
                                                     h + EMBED, 2048, EMBED, 1024);

    const size_t QKV_TILES = (size_t)6 * 24 * 4096;   // per-weight blob count in wqkv_pk

    for (int L = 0; L < DEPTH; ++L) {
        const size_t EE = (size_t)EMBED * EMBED;
        const size_t EM = (size_t)EMBED * MLP_DIM;
        // weight packing for this layer
        pack_KN_kernel<<<dim3(6, 24),  256, 0, stream>>>(wq + L * EE, wqkv_pk,                 EMBED, EMBED);
        pack_KN_kernel<<<dim3(6, 24),  256, 0, stream>>>(wk + L * EE, wqkv_pk + QKV_TILES,     EMBED, EMBED);
        pack_KN_kernel<<<dim3(6, 24),  256, 0, stream>>>(wv + L * EE, wqkv_pk + 2 * QKV_TILES, EMBED, EMBED);
        pack_KN_kernel<<<dim3(6, 24),  256, 0, stream>>>(wo + L * EE, wo_pk,                   EMBED, EMBED);
        pack_KN_kernel<<<dim3(24, 24), 256, 0, stream>>>(w1 + L * EM, w1_pk,                   MLP_DIM, EMBED);
        pack_KN_kernel<<<dim3(6, 96),  256, 0, stream>>>(w2 + L * EM, w2_pk,                   EMBED, MLP_DIM);

        // LN1 -> bf16
        ln_kernel<true><<<N_REAL, 256, 0, stream>>>(h, xln_bf, ln1w + (size_t)L * EMBED,
                                                    ln1b + (size_t)L * EMBED, N_REAL);
        // fused QKV -> bf16
        gemm_bf16<0, 2><<<dim3(18, 17), 256, 0, stream>>>(xln_bf, wqkv_pk, bqkv + (size_t)L * 2304,
                                                          qkv_bf, N_REAL, 2304, EMBED);
        // dilated attention
        attn_kernel<<<dim3(36, 12), 256, 0, stream>>>(qkv_bf, Obr, Lbr);
        combine_kernel<<<((N_REAL * EMBED) + 255) / 256, 256, 0, stream>>>(Obr, Lbr, attn_bf);
        // O-projection + residual
        gemm_bf16<0, 1><<<dim3(6, 17), 256, 0, stream>>>(attn_bf, wo_pk, bo + (size_t)L * EMBED,
                                                         h, N_REAL, EMBED, EMBED);
        // LN2 + MLP + residual
        ln_kernel<true><<<N_REAL, 256, 0, stream>>>(h, xln_bf, ln2w + (size_t)L * EMBED,
                                                    ln2b + (size_t)L * EMBED, N_REAL);
        gemm_bf16<1, 2><<<dim3(24, 17), 256, 0, stream>>>(xln_bf, w1_pk, b1 + (size_t)L * MLP_DIM,
                                                          mid_bf, N_REAL, MLP_DIM, EMBED);
        gemm_bf16<0, 1><<<dim3(6, 17), 256, 0, stream>>>(mid_bf, w2_pk, b2 + (size_t)L * EMBED,
                                                         h, N_REAL, EMBED, MLP_DIM);
    }

    // final LN on row 0 -> d_out (768 fp32)
    ln_kernel<false><<<1, 256, 0, stream>>>(h, (float*)d_out, lnfw, lnfb, 1);
}

// Round 6
// 1453.245 us; speedup vs baseline: 1.2267x; 1.2267x over previous
//
#include <hip/hip_runtime.h>
#include <math.h>

#define EMBED 768
#define HEADS 12
#define DH 64
#define DEPTH 6
#define MLP_DIM 3072
#define N_REAL 2049
#define SP 2112            // fp32 buffer row padding (33*64)
#define SPAD 2176          // bf16 activation row padding
#define NEGV (-1e9f)

typedef __attribute__((ext_vector_type(8))) short short8;
typedef __attribute__((ext_vector_type(4))) float f32x4;

__device__ __forceinline__ unsigned short f2bf(float f) {
    union { float f; unsigned u; } x; x.f = f;
    unsigned r = x.u + 0x7FFF + ((x.u >> 16) & 1);
    return (unsigned short)(r >> 16);
}
__device__ __forceinline__ float bf2f(unsigned short s) {
    union { unsigned u; float f; } x; x.u = (unsigned)s << 16;
    return x.f;
}

// packed fragment-blob index: blobs of 16 "major" (row for A / col for B) x 32 k.
// entry (l*8+e) of blob = element (major = l&15, k = (l>>4)*8 + e).
// pidx(major, k): blob = (major>>4)*nkt + (k>>5); lane = ((k>>3)&3)*16 + (major&15); e = k&7
__device__ __forceinline__ size_t pidx(int mj, int k, int nkt) {
    return (((size_t)(mj >> 4) * nkt + (k >> 5)) << 9) + (size_t)((((k >> 3) & 3) * 16 + (mj & 15)) * 8 + (k & 7));
}

// ---------------- im2col: x -> packed patch blobs (A-layout, nkt=32) ----------------
__global__ void im2col_kernel(const float* __restrict__ x, unsigned short* __restrict__ p) {
    const int pi = blockIdx.x;            // 0..2047
    const int d = pi >> 8, rr = (pi >> 4) & 15, cc = pi & 15;
    const int t = threadIdx.x;            // 256
    #pragma unroll
    for (int u = 0; u < 4; ++u) {
        int i = u * 256 + t;              // 0..1023
        int kd = i >> 8, kr = (i >> 4) & 15, kc = i & 15;
        float v = x[(size_t)(d * 4 + kd) * 65536 + (rr * 16 + kr) * 256 + (cc * 16 + kc)];
        p[pidx(pi, i, 32)] = f2bf(v);
    }
}

// ---------------- weight pack: fp32 [K][N] -> fragment blobs (B-layout) ----------------
// block: 128 N-cols x 32 k; 256 threads; out: 8 blobs of 1KB.
__global__ void pack_KN_kernel(const float* __restrict__ src, unsigned short* __restrict__ dst,
                               int N, int K) {
    __shared__ float lf[128][33];         // [n][k]
    const int bn = blockIdx.x, bk = blockIdx.y;
    const int t = threadIdx.x;
    {
        const int kk = t >> 3, ch = t & 7;
        const float4* s = (const float4*)(src + (size_t)(bk * 32 + kk) * N + bn * 128 + ch * 16);
        float4 v0 = s[0], v1 = s[1], v2 = s[2], v3 = s[3];
        float tmp[16];
        ((float4*)tmp)[0] = v0; ((float4*)tmp)[1] = v1; ((float4*)tmp)[2] = v2; ((float4*)tmp)[3] = v3;
        #pragma unroll
        for (int u = 0; u < 16; ++u) lf[ch * 16 + u][kk] = tmp[u];
    }
    __syncthreads();
    const int nkt = K >> 5;
    const int cg = t >> 5;                // blob 0..7
    const int l0 = (t & 31) * 2;
    unsigned short* o = dst + (((size_t)(bn * 8 + cg) * nkt + bk) << 9);
    #pragma unroll
    for (int q = 0; q < 2; ++q) {
        const int l = l0 + q;
        const int col = cg * 16 + (l & 15), kb = (l >> 4) * 8;
        unsigned short ov[8];
        #pragma unroll
        for (int e = 0; e < 8; ++e) ov[e] = f2bf(lf[col][kb + e]);
        *(short8*)(o + l * 8) = *(short8*)ov;
    }
}

// pack from fp32 [N][K] (conv_w: [768][1024])
__global__ void pack_NK_kernel(const float* __restrict__ src, unsigned short* __restrict__ dst,
                               int N, int K) {
    __shared__ float lf[128][33];
    const int bn = blockIdx.x, bk = blockIdx.y;
    const int t = threadIdx.x;
    {
        const int row = t >> 1, hf = t & 1;
        const float4* s = (const float4*)(src + (size_t)(bn * 128 + row) * K + bk * 32 + hf * 16);
        float4 v0 = s[0], v1 = s[1], v2 = s[2], v3 = s[3];
        float tmp[16];
        ((float4*)tmp)[0] = v0; ((float4*)tmp)[1] = v1; ((float4*)tmp)[2] = v2; ((float4*)tmp)[3] = v3;
        #pragma unroll
        for (int u = 0; u < 16; ++u) lf[row][hf * 16 + u] = tmp[u];
    }
    __syncthreads();
    const int nkt = K >> 5;
    const int cg = t >> 5;
    const int l0 = (t & 31) * 2;
    unsigned short* o = dst + (((size_t)(bn * 8 + cg) * nkt + bk) << 9);
    #pragma unroll
    for (int q = 0; q < 2; ++q) {
        const int l = l0 + q;
        const int col = cg * 16 + (l & 15), kb = (l >> 4) * 8;
        unsigned short ov[8];
        #pragma unroll
        for (int e = 0; e < 8; ++e) ov[e] = f2bf(lf[col][kb + e]);
        *(short8*)(o + l * 8) = *(short8*)ov;
    }
}

// ---------------- qkv bias concat (all layers) ----------------
__global__ void concat_bias_kernel(const float* __restrict__ bq, const float* __restrict__ bk,
                                   const float* __restrict__ bv, float* __restrict__ bqkv) {
    int i = blockIdx.x * 256 + threadIdx.x;
    if (i >= DEPTH * 2304) return;
    int L = i / 2304, j = i - L * 2304;
    float v = (j < 768) ? bq[L * 768 + j] : (j < 1536) ? bk[L * 768 + j - 768] : bv[L * 768 + j - 1536];
    bqkv[i] = v;
}

__global__ void cls_init_kernel(const float* __restrict__ cls,
                                const float* __restrict__ pos,
                                float* __restrict__ h) {
    int e = blockIdx.x * 256 + threadIdx.x;
    if (e < EMBED) h[e] = cls[e] + pos[e];
}

// ---------------- layernorm: one block per row; packed-bf16 (nkt=24) or fp32 out ----------------
template<bool PACKED>
__global__ void ln_kernel(const float* __restrict__ in, void* __restrict__ outv,
                          const float* __restrict__ w, const float* __restrict__ b,
                          int M) {
    int row = blockIdx.x;
    if (row >= M) return;
    const float* xr = in + (size_t)row * EMBED;
    int tid = threadIdx.x;
    float v0 = xr[tid], v1 = xr[tid + 256], v2 = xr[tid + 512];
    __shared__ float red[4];
    float s = v0 + v1 + v2;
    #pragma unroll
    for (int o = 32; o > 0; o >>= 1) s += __shfl_down(s, o);
    if ((tid & 63) == 0) red[tid >> 6] = s;
    __syncthreads();
    float mean = (red[0] + red[1] + red[2] + red[3]) * (1.0f / 768.0f);
    __syncthreads();
    float d0 = v0 - mean, d1 = v1 - mean, d2 = v2 - mean;
    float q2 = d0 * d0 + d1 * d1 + d2 * d2;
    #pragma unroll
    for (int o = 32; o > 0; o >>= 1) q2 += __shfl_down(q2, o);
    if ((tid & 63) == 0) red[tid >> 6] = q2;
    __syncthreads();
    float var = (red[0] + red[1] + red[2] + red[3]) * (1.0f / 768.0f);
    float rstd = 1.0f / sqrtf(var + 1e-5f);
    float o0 = d0 * rstd * w[tid]       + b[tid];
    float o1 = d1 * rstd * w[tid + 256] + b[tid + 256];
    float o2 = d2 * rstd * w[tid + 512] + b[tid + 512];
    if (PACKED) {
        unsigned short* o = (unsigned short*)outv;
        o[pidx(row, tid,       24)] = f2bf(o0);
        o[pidx(row, tid + 256, 24)] = f2bf(o1);
        o[pidx(row, tid + 512, 24)] = f2bf(o2);
    } else {
        float* orow = (float*)outv + (size_t)row * EMBED;
        orow[tid] = o0; orow[tid + 256] = o1; orow[tid + 512] = o2;
    }
}

// ---------------- bf16 MFMA GEMM: LDS-free, fragment-packed operands ----------------
// Apk / Bpk: fragment blobs (A: rows, B: cols). One wave per 64x64 output tile.
// Per K-iter: 8 coalesced 1KB dwordx4 loads straight to VGPR fragments + 16 MFMA.
// 2-tile register prefetch; compiler manages counted vmcnt. No LDS, no barriers.
// MODE: 1 accum fp32 row-major, 2 store bf16 row-major, 3 store bf16 packed (nkt=N/32).
template<int ACT, int MODE>
__global__ __launch_bounds__(64)
void gemm_bf16(const unsigned short* __restrict__ Apk, const unsigned short* __restrict__ Bpk,
               const float* __restrict__ bias, void* __restrict__ Cv,
               int M, int N, int K) {
    const int lane = threadIdx.x;
    const int row0 = blockIdx.y * 64, col0 = blockIdx.x * 64;
    const int nkt = K >> 5;

    f32x4 acc[4][4];
    #pragma unroll
    for (int mi = 0; mi < 4; ++mi)
        #pragma unroll
        for (int ni = 0; ni < 4; ++ni)
            #pragma unroll
            for (int j = 0; j < 4; ++j) acc[mi][ni][j] = 0.0f;

    const unsigned short* Ab[4];
    const unsigned short* Bb[4];
    #pragma unroll
    for (int i = 0; i < 4; ++i) {
        Ab[i] = Apk + (((size_t)(blockIdx.y * 4 + i) * nkt) << 9) + lane * 8;
        Bb[i] = Bpk + (((size_t)(blockIdx.x * 4 + i) * nkt) << 9) + lane * 8;
    }

    short8 a0[4], b0[4], a1[4], b1[4];
    auto LOADT = [&](int t, short8* aa, short8* bb) {
        #pragma unroll
        for (int i = 0; i < 4; ++i) {
            aa[i] = *(const short8*)(Ab[i] + (size_t)t * 512);
            bb[i] = *(const short8*)(Bb[i] + (size_t)t * 512);
        }
    };
    auto MF = [&](short8* aa, short8* bb) {
        #pragma unroll
        for (int mi = 0; mi < 4; ++mi)
            #pragma unroll
            for (int ni = 0; ni < 4; ++ni)
                acc[mi][ni] = __builtin_amdgcn_mfma_f32_16x16x32_bf16(aa[mi], bb[ni], acc[mi][ni], 0, 0, 0);
    };

    LOADT(0, a0, b0);
    for (int t = 0; t < nkt; t += 2) {       // nkt is even (24/32/96)
        LOADT(t + 1, a1, b1);
        MF(a0, b0);
        if (t + 2 < nkt) LOADT(t + 2, a0, b0);
        MF(a1, b1);
    }

    float* Cf = (float*)Cv;
    unsigned short* Cb = (unsigned short*)Cv;
    const int ln15 = lane & 15, kq = lane >> 4;
    const int nktN = N >> 5;
    #pragma unroll
    for (int mi = 0; mi < 4; ++mi) {
        #pragma unroll
        for (int ni = 0; ni < 4; ++ni) {
            const int col = col0 + ni * 16 + ln15;
            const float bb = bias[col];
            #pragma unroll
            for (int j = 0; j < 4; ++j) {
                const int row = row0 + mi * 16 + kq * 4 + j;
                if (row < M) {
                    float v = acc[mi][ni][j] + bb;
                    if (ACT == 1) v = 0.5f * v * (1.0f + erff(v * 0.70710678118654752f));
                    if (MODE == 1)      Cf[(size_t)row * N + col] += v;
                    else if (MODE == 2) Cb[(size_t)row * N + col] = f2bf(v);
                    else                Cb[pidx(row, col, nktN)] = f2bf(v);
                }
            }
        }
    }
}

// ---------------- dilated attention (bf16 qkv in, bf16 Obr out) ----------------
__global__ __launch_bounds__(256, 1)
void attn_kernel(const unsigned short* __restrict__ qkv,
                 unsigned short* __restrict__ Obr, float* __restrict__ Lbr) {
    const int bx = blockIdx.x, hh = blockIdx.y;
    int b, n;
    if      (bx < 17) { b = 0; n = bx; }
    else if (bx < 26) { b = 1; n = bx - 17; }
    else if (bx < 31) { b = 2; n = bx - 26; }
    else if (bx < 34) { b = 3; n = bx - 31; }
    else              { b = 4; n = bx - 34; }
    const int r = 1 << b;
    const int w = 128 << b;
    const int hb = hh & (r - 1);
    const int base = n * w + hb;

    __shared__ float ks[128][64];
    __shared__ float vs[128][64];
    const int tid = threadIdx.x;
    {
        int j = tid >> 1, hf = tid & 1;
        int pos = base + r * j;
        float* kd = &ks[j][hf * 32];
        float* vd = &vs[j][hf * 32];
        if (pos < N_REAL) {
            const short8* kp = (const short8*)(qkv + (size_t)pos * 2304 + 768  + hh * 64 + hf * 32);
            const short8* vp = (const short8*)(qkv + (size_t)pos * 2304 + 1536 + hh * 64 + hf * 32);
            #pragma unroll
            for (int u = 0; u < 4; ++u) {
                short8 kv = kp[u], vv = vp[u];
                #pragma unroll
                for (int e = 0; e < 8; ++e) {
                    kd[u * 8 + e] = bf2f((unsigned short)kv[e]);
                    vd[u * 8 + e] = bf2f((unsigned short)vv[e]);
                }
            }
        } else {
            #pragma unroll
            for (int u = 0; u < 32; ++u) { kd[u] = 0.f; vd[u] = 0.f; }
        }
    }
    __syncthreads();

    const int qi = tid >> 1, hf = tid & 1;
    const int qpos = base + r * qi;

    float qr[64];
    if (qpos < N_REAL) {
        const short8* qs = (const short8*)(qkv + (size_t)qpos * 2304 + hh * 64);
        #pragma unroll
        for (int u = 0; u < 8; ++u) {
            short8 qv = qs[u];
            #pragma unroll
            for (int e = 0; e < 8; ++e) qr[u * 8 + e] = bf2f((unsigned short)qv[e]);
        }
    } else {
        #pragma unroll
        for (int u = 0; u < 64; ++u) qr[u] = 0.f;
    }

    float s[64];
    const float scale = 0.125f;
    #pragma unroll
    for (int jj = 0; jj < 64; ++jj) {
        const int key = hf * 64 + jj;
        const int kpos = base + r * key;
        float acc = 0.f;
        const float4* kr4 = (const float4*)&ks[key][0];
        #pragma unroll
        for (int u = 0; u < 16; ++u) {
            float4 t = kr4[u];
            acc += qr[4*u] * t.x + qr[4*u+1] * t.y + qr[4*u+2] * t.z + qr[4*u+3] * t.w;
        }
        s[jj] = (kpos < N_REAL) ? acc * scale : NEGV;
    }
    float m = NEGV;
    #pragma unroll
    for (int jj = 0; jj < 64; ++jj) m = fmaxf(m, s[jj]);
    m = fmaxf(m, __shfl_xor(m, 1));
    float sum = 0.f;
    #pragma unroll
    for (int jj = 0; jj < 64; ++jj) { s[jj] = expf(s[jj] - m); sum += s[jj]; }
    sum += __shfl_xor(sum, 1);
    float o[64];
    #pragma unroll
    for (int u = 0; u < 64; ++u) o[u] = 0.f;
    #pragma unroll
    for (int jj = 0; jj < 64; ++jj) {
        const int key = hf * 64 + jj;
        const float p = s[jj];
        const float4* vr4 = (const float4*)&vs[key][0];
        #pragma unroll
        for (int u = 0; u < 16; ++u) {
            float4 t = vr4[u];
            o[4*u]   += p * t.x;
            o[4*u+1] += p * t.y;
            o[4*u+2] += p * t.z;
            o[4*u+3] += p * t.w;
        }
    }
    #pragma unroll
    for (int u = 0; u < 64; ++u) o[u] += __shfl_xor(o[u], 1);

    if (hf == 0 && qpos < N_REAL) {
        float inv = 1.0f / sum;
        unsigned short* od = Obr + ((size_t)b * N_REAL + qpos) * EMBED + hh * 64;
        #pragma unroll
        for (int u = 0; u < 64; ++u) od[u] = f2bf(o[u] * inv);
        Lbr[((size_t)b * SP + qpos) * HEADS + hh] = m + logf(sum);
    }
}

// ---------------- branch combine -> packed bf16 (A-layout, nkt=24) ----------------
__global__ void combine_kernel(const unsigned short* __restrict__ Obr, const float* __restrict__ Lbr,
                               unsigned short* __restrict__ out) {
    int gid = blockIdx.x * 256 + threadIdx.x;
    if (gid >= N_REAL * EMBED) return;
    int p = gid / EMBED, e = gid - p * EMBED;
    int h = e >> 6;
    float l[5];
    float mx = NEGV;
    #pragma unroll
    for (int b = 0; b < 5; ++b) {
        const int rm = (1 << b) - 1;
        l[b] = ((p & rm) == (h & rm)) ? Lbr[((size_t)b * SP + p) * HEADS + h] : NEGV;
        mx = fmaxf(mx, l[b]);
    }
    float wsum = 0.f, acc = 0.f;
    #pragma unroll
    for (int b = 0; b < 5; ++b) {
        if (l[b] > NEGV * 0.5f) {
            float wt = expf(l[b] - mx);
            wsum += wt;
            acc += wt * bf2f(Obr[((size_t)b * N_REAL + p) * EMBED + e]);
        }
    }
    out[pidx(p, e, 24)] = f2bf(acc / wsum);
}

// ---------------- host orchestration ----------------
extern "C" void kernel_launch(void* const* d_in, const int* in_sizes, int n_in,
                              void* d_out, int out_size, void* d_ws, size_t ws_size,
                              hipStream_t stream) {
    const float* x      = (const float*)d_in[0];
    const float* conv_w = (const float*)d_in[1];
    const float* conv_b = (const float*)d_in[2];
    const float* cls    = (const float*)d_in[3];
    const float* pos    = (const float*)d_in[4];
    const float* ln1w   = (const float*)d_in[5];
    const float* ln1b   = (const float*)d_in[6];
    const float* wq     = (const float*)d_in[7];
    const float* bq     = (const float*)d_in[8];
    const float* wk     = (const float*)d_in[9];
    const float* bk     = (const float*)d_in[10];
    const float* wv     = (const float*)d_in[11];
    const float* bv     = (const float*)d_in[12];
    const float* wo     = (const float*)d_in[13];
    const float* bo     = (const float*)d_in[14];
    const float* ln2w   = (const float*)d_in[15];
    const float* ln2b   = (const float*)d_in[16];
    const float* w1     = (const float*)d_in[17];
    const float* b1     = (const float*)d_in[18];
    const float* w2     = (const float*)d_in[19];
    const float* b2     = (const float*)d_in[20];
    const float* lnfw   = (const float*)d_in[21];
    const float* lnfb   = (const float*)d_in[22];

    float* ws = (float*)d_ws;
    // fp32 buffers
    float* h     = ws;  ws += (size_t)SP * EMBED;            // residual stream
    float* Lbr   = ws;  ws += (size_t)5 * SP * HEADS;
    float* bqkv  = ws;  ws += (size_t)DEPTH * 2304;
    // bf16 buffers (ushort counts = 2x float words)
    unsigned short* qkv_bf   = (unsigned short*)ws;  ws += (size_t)SPAD * 2304 / 2;    // row-major (attn)
    unsigned short* xln_pk   = (unsigned short*)ws;  ws += (size_t)SPAD * EMBED / 2;   // packed A
    unsigned short* attn_pk  = (unsigned short*)ws;  ws += (size_t)SPAD * EMBED / 2;   // packed A
    unsigned short* mid_pk   = (unsigned short*)ws;  ws += (size_t)SPAD * MLP_DIM / 2; // packed A
    unsigned short* patch_pk = (unsigned short*)ws;  ws += (size_t)2048 * 1024 / 2;    // packed A
    unsigned short* convw_pk = (unsigned short*)ws;  ws += (size_t)EMBED * 1024 / 2;   // packed B
    unsigned short* Obr      = (unsigned short*)ws;  ws += (size_t)5 * N_REAL * EMBED / 2 + 64;
    unsigned short* wqkv_pk  = (unsigned short*)ws;  ws += (size_t)2304 * EMBED / 2;   // packed B
    unsigned short* wo_pk    = (unsigned short*)ws;  ws += (size_t)EMBED * EMBED / 2;  // packed B
    unsigned short* w1_pk    = (unsigned short*)ws;  ws += (size_t)MLP_DIM * EMBED / 2;// packed B
    unsigned short* w2_pk    = (unsigned short*)ws;  ws += (size_t)EMBED * MLP_DIM / 2;// packed B

    // ---- embed ----
    im2col_kernel<<<2048, 256, 0, stream>>>(x, patch_pk);
    pack_NK_kernel<<<dim3(6, 32), 256, 0, stream>>>(conv_w, convw_pk, EMBED, 1024);
    concat_bias_kernel<<<(DEPTH * 2304 + 255) / 256, 256, 0, stream>>>(bq, bk, bv, bqkv);
    cls_init_kernel<<<3, 256, 0, stream>>>(cls, pos, h);
    hipMemcpyAsync(h + EMBED, pos + EMBED, (size_t)2048 * EMBED * sizeof(float),
                   hipMemcpyDeviceToDevice, stream);
    // patch GEMM: h(rows 1..2048) += patches @ conv_w^T + conv_b
    gemm_bf16<0, 1><<<dim3(12, 32), 64, 0, stream>>>(patch_pk, convw_pk, conv_b,
                                                     h + EMBED, 2048, EMBED, 1024);

    const size_t EEpk = (size_t)EMBED * EMBED;   // ushort count of one 768x768 packed weight

    for (int L = 0; L < DEPTH; ++L) {
        const size_t EE = (size_t)EMBED * EMBED;
        const size_t EM = (size_t)EMBED * MLP_DIM;
        // weight packing for this layer (fragment-blob layout)
        pack_KN_kernel<<<dim3(6, 24),  256, 0, stream>>>(wq + L * EE, wqkv_pk,            EMBED, EMBED);
        pack_KN_kernel<<<dim3(6, 24),  256, 0, stream>>>(wk + L * EE, wqkv_pk + EEpk,     EMBED, EMBED);
        pack_KN_kernel<<<dim3(6, 24),  256, 0, stream>>>(wv + L * EE, wqkv_pk + 2 * EEpk, EMBED, EMBED);
        pack_KN_kernel<<<dim3(6, 24),  256, 0, stream>>>(wo + L * EE, wo_pk,              EMBED, EMBED);
        pack_KN_kernel<<<dim3(24, 24), 256, 0, stream>>>(w1 + L * EM, w1_pk,              MLP_DIM, EMBED);
        pack_KN_kernel<<<dim3(6, 96),  256, 0, stream>>>(w2 + L * EM, w2_pk,              EMBED, MLP_DIM);

        // LN1 -> packed bf16
        ln_kernel<true><<<N_REAL, 256, 0, stream>>>(h, xln_pk, ln1w + (size_t)L * EMBED,
                                                    ln1b + (size_t)L * EMBED, N_REAL);
        // fused QKV -> row-major bf16 (for attn)
        gemm_bf16<0, 2><<<dim3(36, 33), 64, 0, stream>>>(xln_pk, wqkv_pk, bqkv + (size_t)L * 2304,
                                                         qkv_bf, N_REAL, 2304, EMBED);
        // dilated attention
        attn_kernel<<<dim3(36, 12), 256, 0, stream>>>(qkv_bf, Obr, Lbr);
        combine_kernel<<<((N_REAL * EMBED) + 255) / 256, 256, 0, stream>>>(Obr, Lbr, attn_pk);
        // O-projection + residual (fp32 accum into h)
        gemm_bf16<0, 1><<<dim3(12, 33), 64, 0, stream>>>(attn_pk, wo_pk, bo + (size_t)L * EMBED,
                                                         h, N_REAL, EMBED, EMBED);
        // LN2 + MLP + residual
        ln_kernel<true><<<N_REAL, 256, 0, stream>>>(h, xln_pk, ln2w + (size_t)L * EMBED,
                                                    ln2b + (size_t)L * EMBED, N_REAL);
        gemm_bf16<1, 3><<<dim3(48, 33), 64, 0, stream>>>(xln_pk, w1_pk, b1 + (size_t)L * MLP_DIM,
                                                         mid_pk, N_REAL, MLP_DIM, EMBED);
        gemm_bf16<0, 1><<<dim3(12, 33), 64, 0, stream>>>(mid_pk, w2_pk, b2 + (size_t)L * EMBED,
                                                         h, N_REAL, EMBED, MLP_DIM);
    }

    // final LN on row 0 -> d_out (768 fp32)
    ln_kernel<false><<<1, 256, 0, stream>>>(h, (float*)d_out, lnfw, lnfb, 1);
}

// Round 7
// 1129.119 us; speedup vs baseline: 1.5788x; 1.2871x over previous
//
#include <hip/hip_runtime.h>
#include <math.h>

#define EMBED 768
#define HEADS 12
#define DH 64
#define DEPTH 6
#define MLP_DIM 3072
#define N_REAL 2049
#define SP 2112            // fp32 buffer row padding (33*64)
#define SPAD 2176          // bf16 activation row padding
#define NEGV (-1e9f)

typedef __attribute__((ext_vector_type(8))) short short8;
typedef __attribute__((ext_vector_type(4))) float f32x4;

__device__ __forceinline__ unsigned short f2bf(float f) {
    union { float f; unsigned u; } x; x.f = f;
    unsigned r = x.u + 0x7FFF + ((x.u >> 16) & 1);
    return (unsigned short)(r >> 16);
}
__device__ __forceinline__ float bf2f(unsigned short s) {
    union { unsigned u; float f; } x; x.u = (unsigned)s << 16;
    return x.f;
}

// packed fragment-blob index: blobs of 16 "major" (row for A / col for B) x 32 k.
// entry (l*8+e) of blob = element (major = l&15, k = (l>>4)*8 + e).
__device__ __forceinline__ size_t pidx(int mj, int k, int nkt) {
    return (((size_t)(mj >> 4) * nkt + (k >> 5)) << 9) + (size_t)((((k >> 3) & 3) * 16 + (mj & 15)) * 8 + (k & 7));
}

// ---------------- im2col: x -> packed patch blobs (A-layout, nkt=32) ----------------
__global__ void im2col_kernel(const float* __restrict__ x, unsigned short* __restrict__ p) {
    const int pi = blockIdx.x;            // 0..2047
    const int d = pi >> 8, rr = (pi >> 4) & 15, cc = pi & 15;
    const int t = threadIdx.x;            // 256
    #pragma unroll
    for (int u = 0; u < 4; ++u) {
        int i = u * 256 + t;              // 0..1023
        int kd = i >> 8, kr = (i >> 4) & 15, kc = i & 15;
        float v = x[(size_t)(d * 4 + kd) * 65536 + (rr * 16 + kr) * 256 + (cc * 16 + kc)];
        p[pidx(pi, i, 32)] = f2bf(v);
    }
}

// ---------------- weight pack: fp32 [K][N] -> fragment blobs (B-layout) ----------------
__global__ void pack_KN_kernel(const float* __restrict__ src, unsigned short* __restrict__ dst,
                               int N, int K) {
    __shared__ float lf[128][33];         // [n][k]
    const int bn = blockIdx.x, bk = blockIdx.y;
    const int t = threadIdx.x;
    {
        const int kk = t >> 3, ch = t & 7;
        const float4* s = (const float4*)(src + (size_t)(bk * 32 + kk) * N + bn * 128 + ch * 16);
        float4 v0 = s[0], v1 = s[1], v2 = s[2], v3 = s[3];
        float tmp[16];
        ((float4*)tmp)[0] = v0; ((float4*)tmp)[1] = v1; ((float4*)tmp)[2] = v2; ((float4*)tmp)[3] = v3;
        #pragma unroll
        for (int u = 0; u < 16; ++u) lf[ch * 16 + u][kk] = tmp[u];
    }
    __syncthreads();
    const int nkt = K >> 5;
    const int cg = t >> 5;                // blob 0..7
    const int l0 = (t & 31) * 2;
    unsigned short* o = dst + (((size_t)(bn * 8 + cg) * nkt + bk) << 9);
    #pragma unroll
    for (int q = 0; q < 2; ++q) {
        const int l = l0 + q;
        const int col = cg * 16 + (l & 15), kb = (l >> 4) * 8;
        unsigned short ov[8];
        #pragma unroll
        for (int e = 0; e < 8; ++e) ov[e] = f2bf(lf[col][kb + e]);
        *(short8*)(o + l * 8) = *(short8*)ov;
    }
}

// pack from fp32 [N][K] (conv_w: [768][1024])
__global__ void pack_NK_kernel(const float* __restrict__ src, unsigned short* __restrict__ dst,
                               int N, int K) {
    __shared__ float lf[128][33];
    const int bn = blockIdx.x, bk = blockIdx.y;
    const int t = threadIdx.x;
    {
        const int row = t >> 1, hf = t & 1;
        const float4* s = (const float4*)(src + (size_t)(bn * 128 + row) * K + bk * 32 + hf * 16);
        float4 v0 = s[0], v1 = s[1], v2 = s[2], v3 = s[3];
        float tmp[16];
        ((float4*)tmp)[0] = v0; ((float4*)tmp)[1] = v1; ((float4*)tmp)[2] = v2; ((float4*)tmp)[3] = v3;
        #pragma unroll
        for (int u = 0; u < 16; ++u) lf[row][hf * 16 + u] = tmp[u];
    }
    __syncthreads();
    const int nkt = K >> 5;
    const int cg = t >> 5;
    const int l0 = (t & 31) * 2;
    unsigned short* o = dst + (((size_t)(bn * 8 + cg) * nkt + bk) << 9);
    #pragma unroll
    for (int q = 0; q < 2; ++q) {
        const int l = l0 + q;
        const int col = cg * 16 + (l & 15), kb = (l >> 4) * 8;
        unsigned short ov[8];
        #pragma unroll
        for (int e = 0; e < 8; ++e) ov[e] = f2bf(lf[col][kb + e]);
        *(short8*)(o + l * 8) = *(short8*)ov;
    }
}

// ---------------- qkv bias concat (all layers) ----------------
__global__ void concat_bias_kernel(const float* __restrict__ bq, const float* __restrict__ bk,
                                   const float* __restrict__ bv, float* __restrict__ bqkv) {
    int i = blockIdx.x * 256 + threadIdx.x;
    if (i >= DEPTH * 2304) return;
    int L = i / 2304, j = i - L * 2304;
    float v = (j < 768) ? bq[L * 768 + j] : (j < 1536) ? bk[L * 768 + j - 768] : bv[L * 768 + j - 1536];
    bqkv[i] = v;
}

__global__ void cls_init_kernel(const float* __restrict__ cls,
                                const float* __restrict__ pos,
                                float* __restrict__ h) {
    int e = blockIdx.x * 256 + threadIdx.x;
    if (e < EMBED) h[e] = cls[e] + pos[e];
}

// ---------------- layernorm: one block per row; packed-bf16 (nkt=24) or fp32 out ----------------
template<bool PACKED>
__global__ void ln_kernel(const float* __restrict__ in, void* __restrict__ outv,
                          const float* __restrict__ w, const float* __restrict__ b,
                          int M) {
    int row = blockIdx.x;
    if (row >= M) return;
    const float* xr = in + (size_t)row * EMBED;
    int tid = threadIdx.x;
    float v0 = xr[tid], v1 = xr[tid + 256], v2 = xr[tid + 512];
    __shared__ float red[4];
    float s = v0 + v1 + v2;
    #pragma unroll
    for (int o = 32; o > 0; o >>= 1) s += __shfl_down(s, o);
    if ((tid & 63) == 0) red[tid >> 6] = s;
    __syncthreads();
    float mean = (red[0] + red[1] + red[2] + red[3]) * (1.0f / 768.0f);
    __syncthreads();
    float d0 = v0 - mean, d1 = v1 - mean, d2 = v2 - mean;
    float q2 = d0 * d0 + d1 * d1 + d2 * d2;
    #pragma unroll
    for (int o = 32; o > 0; o >>= 1) q2 += __shfl_down(q2, o);
    if ((tid & 63) == 0) red[tid >> 6] = q2;
    __syncthreads();
    float var = (red[0] + red[1] + red[2] + red[3]) * (1.0f / 768.0f);
    float rstd = 1.0f / sqrtf(var + 1e-5f);
    float o0 = d0 * rstd * w[tid]       + b[tid];
    float o1 = d1 * rstd * w[tid + 256] + b[tid + 256];
    float o2 = d2 * rstd * w[tid + 512] + b[tid + 512];
    if (PACKED) {
        unsigned short* o = (unsigned short*)outv;
        o[pidx(row, tid,       24)] = f2bf(o0);
        o[pidx(row, tid + 256, 24)] = f2bf(o1);
        o[pidx(row, tid + 512, 24)] = f2bf(o2);
    } else {
        float* orow = (float*)outv + (size_t)row * EMBED;
        orow[tid] = o0; orow[tid + 256] = o1; orow[tid + 512] = o2;
    }
}

// ---------------- bf16 MFMA GEMM: LDS-free, fragment-packed operands ----------------
template<int ACT, int MODE>
__global__ __launch_bounds__(64)
void gemm_bf16(const unsigned short* __restrict__ Apk, const unsigned short* __restrict__ Bpk,
               const float* __restrict__ bias, void* __restrict__ Cv,
               int M, int N, int K) {
    const int lane = threadIdx.x;
    const int row0 = blockIdx.y * 64, col0 = blockIdx.x * 64;
    const int nkt = K >> 5;

    f32x4 acc[4][4];
    #pragma unroll
    for (int mi = 0; mi < 4; ++mi)
        #pragma unroll
        for (int ni = 0; ni < 4; ++ni)
            #pragma unroll
            for (int j = 0; j < 4; ++j) acc[mi][ni][j] = 0.0f;

    const unsigned short* Ab[4];
    const unsigned short* Bb[4];
    #pragma unroll
    for (int i = 0; i < 4; ++i) {
        Ab[i] = Apk + (((size_t)(blockIdx.y * 4 + i) * nkt) << 9) + lane * 8;
        Bb[i] = Bpk + (((size_t)(blockIdx.x * 4 + i) * nkt) << 9) + lane * 8;
    }

    short8 a0[4], b0[4], a1[4], b1[4];
    auto LOADT = [&](int t, short8* aa, short8* bb) {
        #pragma unroll
        for (int i = 0; i < 4; ++i) {
            aa[i] = *(const short8*)(Ab[i] + (size_t)t * 512);
            bb[i] = *(const short8*)(Bb[i] + (size_t)t * 512);
        }
    };
    auto MF = [&](short8* aa, short8* bb) {
        #pragma unroll
        for (int mi = 0; mi < 4; ++mi)
            #pragma unroll
            for (int ni = 0; ni < 4; ++ni)
                acc[mi][ni] = __builtin_amdgcn_mfma_f32_16x16x32_bf16(aa[mi], bb[ni], acc[mi][ni], 0, 0, 0);
    };

    LOADT(0, a0, b0);
    for (int t = 0; t < nkt; t += 2) {       // nkt is even (24/32/96)
        LOADT(t + 1, a1, b1);
        MF(a0, b0);
        if (t + 2 < nkt) LOADT(t + 2, a0, b0);
        MF(a1, b1);
    }

    float* Cf = (float*)Cv;
    unsigned short* Cb = (unsigned short*)Cv;
    const int ln15 = lane & 15, kq = lane >> 4;
    const int nktN = N >> 5;
    #pragma unroll
    for (int mi = 0; mi < 4; ++mi) {
        #pragma unroll
        for (int ni = 0; ni < 4; ++ni) {
            const int col = col0 + ni * 16 + ln15;
            const float bb = bias[col];
            #pragma unroll
            for (int j = 0; j < 4; ++j) {
                const int row = row0 + mi * 16 + kq * 4 + j;
                if (row < M) {
                    float v = acc[mi][ni][j] + bb;
                    if (ACT == 1) v = 0.5f * v * (1.0f + erff(v * 0.70710678118654752f));
                    if (MODE == 1)      Cf[(size_t)row * N + col] += v;
                    else if (MODE == 2) Cb[(size_t)row * N + col] = f2bf(v);
                    else                Cb[pidx(row, col, nktN)] = f2bf(v);
                }
            }
        }
    }
}

// ---------------- dilated attention: MFMA (bf16 qkv in, bf16 Obr out) ----------------
// Block = (branch-seg, head): 128 dilated q x 128 dilated k, D=64.
// Wave w owns q rows w*32..w*32+31 (full 128-k): softmax is wave-local.
// QK^T: A=Q frags, B=K frags direct from global (row-major 16B/lane).
// P -> bf16 LDS (XOR swizzle (row&7)<<4); V^T staged swizzled; PV via MFMA.
__global__ __launch_bounds__(256, 1)
void attn_kernel(const unsigned short* __restrict__ qkv,
                 unsigned short* __restrict__ Obr, float* __restrict__ Lbr) {
    const int bx = blockIdx.x, hh = blockIdx.y;
    int b, n;
    if      (bx < 17) { b = 0; n = bx; }
    else if (bx < 26) { b = 1; n = bx - 17; }
    else if (bx < 31) { b = 2; n = bx - 26; }
    else if (bx < 34) { b = 3; n = bx - 31; }
    else              { b = 4; n = bx - 34; }
    const int r = 1 << b;
    const int segw = 128 << b;
    const int base = n * segw + (hh & (r - 1));

    __shared__ __attribute__((aligned(16))) unsigned short VT[64 * 128];   // [d][k] swizzled
    __shared__ __attribute__((aligned(16))) unsigned short Pl[128 * 128];  // [q][k] swizzled

    const int tid = threadIdx.x;

    // ---- stage V^T (transposed + swizzled) ----
    {
        const int key = tid >> 1, dh2 = (tid & 1) * 32;
        const int pos = base + r * key;
        const bool val = pos < N_REAL;
        const unsigned short* vsrc = qkv + (size_t)(val ? pos : 0) * 2304 + 1536 + hh * 64 + dh2;
        #pragma unroll
        for (int u = 0; u < 4; ++u) {
            short8 vv = ((const short8*)vsrc)[u];
            #pragma unroll
            for (int e = 0; e < 8; ++e) {
                const int d = dh2 + u * 8 + e;
                VT[(d * 256 + ((key * 2) ^ ((d & 7) << 4))) >> 1] =
                    val ? (unsigned short)vv[e] : (unsigned short)0;
            }
        }
    }
    __syncthreads();

    const int lane = tid & 63, wv = tid >> 6;
    const int ln15 = lane & 15, kq = lane >> 4;

    // ---- QK^T ----
    f32x4 sc[2][8];
    #pragma unroll
    for (int mi = 0; mi < 2; ++mi)
        #pragma unroll
        for (int ni = 0; ni < 8; ++ni)
            #pragma unroll
            for (int j = 0; j < 4; ++j) sc[mi][ni][j] = 0.0f;

    #pragma unroll
    for (int kt = 0; kt < 2; ++kt) {
        short8 qfr[2], kfr[8];
        #pragma unroll
        for (int mi = 0; mi < 2; ++mi) {
            const int pos = base + r * (wv * 32 + mi * 16 + ln15);
            qfr[mi] = *(const short8*)(qkv + (size_t)(pos < N_REAL ? pos : 0) * 2304
                                       + hh * 64 + kt * 32 + kq * 8);
        }
        #pragma unroll
        for (int ni = 0; ni < 8; ++ni) {
            const int pos = base + r * (ni * 16 + ln15);
            kfr[ni] = *(const short8*)(qkv + (size_t)(pos < N_REAL ? pos : 0) * 2304
                                       + 768 + hh * 64 + kt * 32 + kq * 8);
        }
        #pragma unroll
        for (int mi = 0; mi < 2; ++mi)
            #pragma unroll
            for (int ni = 0; ni < 8; ++ni)
                sc[mi][ni] = __builtin_amdgcn_mfma_f32_16x16x32_bf16(qfr[mi], kfr[ni], sc[mi][ni], 0, 0, 0);
    }

    // scale + key mask (col = ni*16 + ln15 for the whole frag)
    #pragma unroll
    for (int ni = 0; ni < 8; ++ni) {
        const bool kval = (base + r * (ni * 16 + ln15)) < N_REAL;
        #pragma unroll
        for (int mi = 0; mi < 2; ++mi)
            #pragma unroll
            for (int j = 0; j < 4; ++j)
                sc[mi][ni][j] = kval ? sc[mi][ni][j] * 0.125f : NEGV;
    }

    // ---- wave-local row softmax (row = mi*16 + kq*4 + j; cols over ni x ln15) ----
    float rsum[2][4];
    #pragma unroll
    for (int mi = 0; mi < 2; ++mi) {
        #pragma unroll
        for (int j = 0; j < 4; ++j) {
            float mx = sc[mi][0][j];
            #pragma unroll
            for (int ni = 1; ni < 8; ++ni) mx = fmaxf(mx, sc[mi][ni][j]);
            mx = fmaxf(mx, __shfl_xor(mx, 1));
            mx = fmaxf(mx, __shfl_xor(mx, 2));
            mx = fmaxf(mx, __shfl_xor(mx, 4));
            mx = fmaxf(mx, __shfl_xor(mx, 8));
            float sm = 0.f;
            #pragma unroll
            for (int ni = 0; ni < 8; ++ni) {
                float e = __expf(sc[mi][ni][j] - mx);
                sc[mi][ni][j] = e;
                sm += e;
            }
            sm += __shfl_xor(sm, 1);
            sm += __shfl_xor(sm, 2);
            sm += __shfl_xor(sm, 4);
            sm += __shfl_xor(sm, 8);
            rsum[mi][j] = sm;
            // lse write (one lane per row)
            const int prow = wv * 32 + mi * 16 + kq * 4 + j;
            const int qpos = base + r * prow;
            if (ln15 == 0 && qpos < N_REAL)
                Lbr[((size_t)b * SP + qpos) * HEADS + hh] = mx + logf(sm);
        }
    }

    // ---- write P to LDS (bf16, swizzled) ----
    #pragma unroll
    for (int mi = 0; mi < 2; ++mi)
        #pragma unroll
        for (int j = 0; j < 4; ++j) {
            const int prow = wv * 32 + mi * 16 + kq * 4 + j;
            #pragma unroll
            for (int ni = 0; ni < 8; ++ni) {
                const int col = ni * 16 + ln15;
                Pl[(prow * 256 + ((col * 2) ^ ((prow & 7) << 4))) >> 1] = f2bf(sc[mi][ni][j]);
            }
        }
    __syncthreads();

    // ---- PV: O[32 q][64 d] per wave, K=128 ----
    f32x4 ov[2][4];
    #pragma unroll
    for (int mi = 0; mi < 2; ++mi)
        #pragma unroll
        for (int ni = 0; ni < 4; ++ni)
            #pragma unroll
            for (int j = 0; j < 4; ++j) ov[mi][ni][j] = 0.0f;

    #pragma unroll
    for (int kt = 0; kt < 4; ++kt) {
        short8 pa[2], vb[4];
        #pragma unroll
        for (int mi = 0; mi < 2; ++mi) {
            const int row = wv * 32 + mi * 16 + ln15;
            pa[mi] = *(const short8*)((const char*)Pl + row * 256
                                      + ((kt * 64 + kq * 16) ^ ((row & 7) << 4)));
        }
        #pragma unroll
        for (int ni = 0; ni < 4; ++ni) {
            const int d = ni * 16 + ln15;
            vb[ni] = *(const short8*)((const char*)VT + d * 256
                                      + ((kt * 64 + kq * 16) ^ ((d & 7) << 4)));
        }
        #pragma unroll
        for (int mi = 0; mi < 2; ++mi)
            #pragma unroll
            for (int ni = 0; ni < 4; ++ni)
                ov[mi][ni] = __builtin_amdgcn_mfma_f32_16x16x32_bf16(pa[mi], vb[ni], ov[mi][ni], 0, 0, 0);
    }

    // ---- epilogue: normalize + store ----
    #pragma unroll
    for (int mi = 0; mi < 2; ++mi)
        #pragma unroll
        for (int j = 0; j < 4; ++j) {
            const int prow = wv * 32 + mi * 16 + kq * 4 + j;
            const int qpos = base + r * prow;
            if (qpos < N_REAL) {
                const float inv = 1.0f / rsum[mi][j];
                #pragma unroll
                for (int ni = 0; ni < 4; ++ni)
                    Obr[((size_t)b * N_REAL + qpos) * EMBED + hh * 64 + ni * 16 + ln15] =
                        f2bf(ov[mi][ni][j] * inv);
            }
        }
}

// ---------------- branch combine -> packed bf16 (A-layout, nkt=24) ----------------
__global__ void combine_kernel(const unsigned short* __restrict__ Obr, const float* __restrict__ Lbr,
                               unsigned short* __restrict__ out) {
    int gid = blockIdx.x * 256 + threadIdx.x;
    if (gid >= N_REAL * EMBED) return;
    int p = gid / EMBED, e = gid - p * EMBED;
    int h = e >> 6;
    float l[5];
    float mx = NEGV;
    #pragma unroll
    for (int b = 0; b < 5; ++b) {
        const int rm = (1 << b) - 1;
        l[b] = ((p & rm) == (h & rm)) ? Lbr[((size_t)b * SP + p) * HEADS + h] : NEGV;
        mx = fmaxf(mx, l[b]);
    }
    float wsum = 0.f, acc = 0.f;
    #pragma unroll
    for (int b = 0; b < 5; ++b) {
        if (l[b] > NEGV * 0.5f) {
            float wt = expf(l[b] - mx);
            wsum += wt;
            acc += wt * bf2f(Obr[((size_t)b * N_REAL + p) * EMBED + e]);
        }
    }
    out[pidx(p, e, 24)] = f2bf(acc / wsum);
}

// ---------------- host orchestration ----------------
extern "C" void kernel_launch(void* const* d_in, const int* in_sizes, int n_in,
                              void* d_out, int out_size, void* d_ws, size_t ws_size,
                              hipStream_t stream) {
    const float* x      = (const float*)d_in[0];
    const float* conv_w = (const float*)d_in[1];
    const float* conv_b = (const float*)d_in[2];
    const float* cls    = (const float*)d_in[3];
    const float* pos    = (const float*)d_in[4];
    const float* ln1w   = (const float*)d_in[5];
    const float* ln1b   = (const float*)d_in[6];
    const float* wq     = (const float*)d_in[7];
    const float* bq     = (const float*)d_in[8];
    const float* wk     = (const float*)d_in[9];
    const float* bk     = (const float*)d_in[10];
    const float* wv     = (const float*)d_in[11];
    const float* bv     = (const float*)d_in[12];
    const float* wo     = (const float*)d_in[13];
    const float* bo     = (const float*)d_in[14];
    const float* ln2w   = (const float*)d_in[15];
    const float* ln2b   = (const float*)d_in[16];
    const float* w1     = (const float*)d_in[17];
    const float* b1     = (const float*)d_in[18];
    const float* w2     = (const float*)d_in[19];
    const float* b2     = (const float*)d_in[20];
    const float* lnfw   = (const float*)d_in[21];
    const float* lnfb   = (const float*)d_in[22];

    float* ws = (float*)d_ws;
    // fp32 buffers
    float* h     = ws;  ws += (size_t)SP * EMBED;            // residual stream
    float* Lbr   = ws;  ws += (size_t)5 * SP * HEADS;
    float* bqkv  = ws;  ws += (size_t)DEPTH * 2304;
    // bf16 buffers
    unsigned short* qkv_bf   = (unsigned short*)ws;  ws += (size_t)SPAD * 2304 / 2;    // row-major (attn)
    unsigned short* xln_pk   = (unsigned short*)ws;  ws += (size_t)SPAD * EMBED / 2;   // packed A
    unsigned short* attn_pk  = (unsigned short*)ws;  ws += (size_t)SPAD * EMBED / 2;   // packed A
    unsigned short* mid_pk   = (unsigned short*)ws;  ws += (size_t)SPAD * MLP_DIM / 2; // packed A
    unsigned short* patch_pk = (unsigned short*)ws;  ws += (size_t)2048 * 1024 / 2;    // packed A
    unsigned short* convw_pk = (unsigned short*)ws;  ws += (size_t)EMBED * 1024 / 2;   // packed B
    unsigned short* Obr      = (unsigned short*)ws;  ws += (size_t)5 * N_REAL * EMBED / 2 + 64;
    unsigned short* wqkv_pk  = (unsigned short*)ws;  ws += (size_t)2304 * EMBED / 2;   // packed B
    unsigned short* wo_pk    = (unsigned short*)ws;  ws += (size_t)EMBED * EMBED / 2;  // packed B
    unsigned short* w1_pk    = (unsigned short*)ws;  ws += (size_t)MLP_DIM * EMBED / 2;// packed B
    unsigned short* w2_pk    = (unsigned short*)ws;  ws += (size_t)EMBED * MLP_DIM / 2;// packed B

    // ---- embed ----
    im2col_kernel<<<2048, 256, 0, stream>>>(x, patch_pk);
    pack_NK_kernel<<<dim3(6, 32), 256, 0, stream>>>(conv_w, convw_pk, EMBED, 1024);
    concat_bias_kernel<<<(DEPTH * 2304 + 255) / 256, 256, 0, stream>>>(bq, bk, bv, bqkv);
    cls_init_kernel<<<3, 256, 0, stream>>>(cls, pos, h);
    hipMemcpyAsync(h + EMBED, pos + EMBED, (size_t)2048 * EMBED * sizeof(float),
                   hipMemcpyDeviceToDevice, stream);
    gemm_bf16<0, 1><<<dim3(12, 32), 64, 0, stream>>>(patch_pk, convw_pk, conv_b,
                                                     h + EMBED, 2048, EMBED, 1024);

    const size_t EEpk = (size_t)EMBED * EMBED;

    for (int L = 0; L < DEPTH; ++L) {
        const size_t EE = (size_t)EMBED * EMBED;
        const size_t EM = (size_t)EMBED * MLP_DIM;
        // weight packing for this layer (fragment-blob layout)
        pack_KN_kernel<<<dim3(6, 24),  256, 0, stream>>>(wq + L * EE, wqkv_pk,            EMBED, EMBED);
        pack_KN_kernel<<<dim3(6, 24),  256, 0, stream>>>(wk + L * EE, wqkv_pk + EEpk,     EMBED, EMBED);
        pack_KN_kernel<<<dim3(6, 24),  256, 0, stream>>>(wv + L * EE, wqkv_pk + 2 * EEpk, EMBED, EMBED);
        pack_KN_kernel<<<dim3(6, 24),  256, 0, stream>>>(wo + L * EE, wo_pk,              EMBED, EMBED);
        pack_KN_kernel<<<dim3(24, 24), 256, 0, stream>>>(w1 + L * EM, w1_pk,              MLP_DIM, EMBED);
        pack_KN_kernel<<<dim3(6, 96),  256, 0, stream>>>(w2 + L * EM, w2_pk,              EMBED, MLP_DIM);

        // LN1 -> packed bf16
        ln_kernel<true><<<N_REAL, 256, 0, stream>>>(h, xln_pk, ln1w + (size_t)L * EMBED,
                                                    ln1b + (size_t)L * EMBED, N_REAL);
        // fused QKV -> row-major bf16 (for attn)
        gemm_bf16<0, 2><<<dim3(36, 33), 64, 0, stream>>>(xln_pk, wqkv_pk, bqkv + (size_t)L * 2304,
                                                         qkv_bf, N_REAL, 2304, EMBED);
        // dilated attention (MFMA)
        attn_kernel<<<dim3(36, 12), 256, 0, stream>>>(qkv_bf, Obr, Lbr);
        combine_kernel<<<((N_REAL * EMBED) + 255) / 256, 256, 0, stream>>>(Obr, Lbr, attn_pk);
        // O-projection + residual (fp32 accum into h)
        gemm_bf16<0, 1><<<dim3(12, 33), 64, 0, stream>>>(attn_pk, wo_pk, bo + (size_t)L * EMBED,
                                                         h, N_REAL, EMBED, EMBED);
        // LN2 + MLP + residual
        ln_kernel<true><<<N_REAL, 256, 0, stream>>>(h, xln_pk, ln2w + (size_t)L * EMBED,
                                                    ln2b + (size_t)L * EMBED, N_REAL);
        gemm_bf16<1, 3><<<dim3(48, 33), 64, 0, stream>>>(xln_pk, w1_pk, b1 + (size_t)L * MLP_DIM,
                                                         mid_pk, N_REAL, MLP_DIM, EMBED);
        gemm_bf16<0, 1><<<dim3(12, 33), 64, 0, stream>>>(mid_pk, w2_pk, b2 + (size_t)L * EMBED,
                                                         h, N_REAL, EMBED, MLP_DIM);
    }

    // final LN on row 0 -> d_out (768 fp32)
    ln_kernel<false><<<1, 256, 0, stream>>>(h, (float*)d_out, lnfw, lnfb, 1);
}